// Round 1
// baseline (1570.290 us; speedup 1.0000x reference)
//
#include <hip/hip_runtime.h>
#include <hip/hip_bf16.h>

namespace {
constexpr int NS   = 64;          // batch
constexpr int NPS  = 802816;      // elements per sample (256*56*56)
constexpr int NPSV = NPS / 4;     // float4 per sample
constexpr unsigned KSEL = 80281u; // int(0.1 * 802816)
constexpr int HB   = 65536;       // histogram bins (high/low 16 bits)
constexpr unsigned SENTINEL = 0xFFFFFFFFu;
constexpr int GX = 64;            // blocks per sample for streaming kernels
}

__global__ void zero4_kernel(uint4* __restrict__ p, int n4) {
    int i = blockIdx.x * blockDim.x + threadIdx.x;
    const int stride = gridDim.x * blockDim.x;
    const uint4 z = {0u, 0u, 0u, 0u};
    for (; i < n4; i += stride) p[i] = z;
}

// Pass 1: product, optional stash of p, histogram of high 16 bits (skip zeros/negatives)
__global__ void hist_hi_kernel(const float4* __restrict__ f, const float4* __restrict__ g,
                               float4* __restrict__ pout, unsigned* __restrict__ hist) {
    const int b = blockIdx.y;
    const size_t base = (size_t)b * NPSV;
    unsigned* __restrict__ h = hist + ((size_t)b << 16);
    const int stride = gridDim.x * blockDim.x;
    const bool store = (pout != nullptr);
    for (int i = blockIdx.x * blockDim.x + threadIdx.x; i < NPSV; i += stride) {
        const float4 fv = f[base + i];
        const float4 gv = g[base + i];
        float4 p;
        p.x = fv.x * gv.x; p.y = fv.y * gv.y; p.z = fv.z * gv.z; p.w = fv.w * gv.w;
        if (store) pout[base + i] = p;
        if (p.x > 0.0f) atomicAdd(&h[__float_as_uint(p.x) >> 16], 1u);
        if (p.y > 0.0f) atomicAdd(&h[__float_as_uint(p.y) >> 16], 1u);
        if (p.z > 0.0f) atomicAdd(&h[__float_as_uint(p.z) >> 16], 1u);
        if (p.w > 0.0f) atomicAdd(&h[__float_as_uint(p.w) >> 16], 1u);
    }
}

struct SelRes { unsigned bin, rem; };

// 256 threads. Find bin T with S(T) < K <= S(T)+h[T], S = count strictly above T.
// Returns {T, K - S(T)}; {SENTINEL, 0} if total count < K.
__device__ SelRes radix_level_select(const unsigned* __restrict__ h, unsigned K) {
    const int t = threadIdx.x;
    __shared__ unsigned cs[256];
    __shared__ unsigned fBin, fRem;
    if (t == 0) { fBin = SENTINEL; fRem = 0u; }
    unsigned s = 0;
    const uint4* hv = reinterpret_cast<const uint4*>(h + t * 256);
    for (int j = 0; j < 64; ++j) { uint4 v = hv[j]; s += v.x + v.y + v.z + v.w; }
    cs[t] = s;
    __syncthreads();
    unsigned suf = 0;  // count in chunks strictly above chunk t
    for (int j = t + 1; j < 256; ++j) suf += cs[j];
    if (suf < K && suf + s >= K) {   // crossing happens inside this thread's chunk
        unsigned curS = suf;
        for (int j = 255; j >= 0; --j) {
            const unsigned c = h[t * 256 + j];
            if (curS < K && curS + c >= K) { fBin = (unsigned)(t * 256 + j); fRem = K - curS; }
            curS += c;
        }
    }
    __syncthreads();
    return SelRes{fBin, fRem};
}

__global__ void scan_hi_kernel(const unsigned* __restrict__ hist,
                               unsigned* __restrict__ candBin, unsigned* __restrict__ kRem) {
    const int b = blockIdx.x;
    SelRes r = radix_level_select(hist + ((size_t)b << 16), KSEL);
    if (threadIdx.x == 0) { candBin[b] = r.bin; kRem[b] = r.rem; }
}

// Pass 2: histogram low 16 bits of elements whose high 16 bits == candBin[b]
__global__ void hist_lo_kernel(const float4* __restrict__ f, const float4* __restrict__ g,
                               const float4* __restrict__ pbuf,
                               const unsigned* __restrict__ candBin,
                               unsigned* __restrict__ hist2) {
    const int b = blockIdx.y;
    const unsigned cb = candBin[b];
    unsigned* __restrict__ h = hist2 + ((size_t)b << 16);
    const size_t base = (size_t)b * NPSV;
    const int stride = gridDim.x * blockDim.x;
    for (int i = blockIdx.x * blockDim.x + threadIdx.x; i < NPSV; i += stride) {
        float4 p;
        if (pbuf) {
            p = pbuf[base + i];
        } else {
            const float4 fv = f[base + i];
            const float4 gv = g[base + i];
            p.x = fv.x * gv.x; p.y = fv.y * gv.y; p.z = fv.z * gv.z; p.w = fv.w * gv.w;
        }
        if (p.x > 0.0f) { unsigned u = __float_as_uint(p.x); if ((u >> 16) == cb) atomicAdd(&h[u & 0xFFFFu], 1u); }
        if (p.y > 0.0f) { unsigned u = __float_as_uint(p.y); if ((u >> 16) == cb) atomicAdd(&h[u & 0xFFFFu], 1u); }
        if (p.z > 0.0f) { unsigned u = __float_as_uint(p.z); if ((u >> 16) == cb) atomicAdd(&h[u & 0xFFFFu], 1u); }
        if (p.w > 0.0f) { unsigned u = __float_as_uint(p.w); if ((u >> 16) == cb) atomicAdd(&h[u & 0xFFFFu], 1u); }
    }
}

__global__ void scan_lo_kernel(const unsigned* __restrict__ hist2,
                               const unsigned* __restrict__ candBin,
                               const unsigned* __restrict__ kRem,
                               float* __restrict__ thrF) {
    const int b = blockIdx.x;
    const unsigned cb = candBin[b];
    const unsigned kr = kRem[b];
    if (cb == SENTINEL || kr == 0u) {   // fewer than K positive elements -> threshold 0
        if (threadIdx.x == 0) thrF[b] = 0.0f;
        return;
    }
    SelRes r = radix_level_select(hist2 + ((size_t)b << 16), kr);
    if (threadIdx.x == 0) {
        const unsigned lo = (r.bin == SENTINEL) ? 0u : r.bin;
        thrF[b] = __uint_as_float((cb << 16) | lo);
    }
}

// Pass 3: out = (p > thr) ? 0 : f   (exactly matches mask = attr <= thr since thr >= 0)
__global__ void apply_kernel(const float4* __restrict__ f, const float4* __restrict__ g,
                             const float4* __restrict__ pbuf,
                             const float* __restrict__ thrF,
                             float4* __restrict__ out, int tailCut) {
    const int b = blockIdx.y;
    const float thr = thrF[b];
    const size_t base = (size_t)b * NPSV;
    const int limit = NPSV - ((b == NS - 1) ? tailCut : 0);
    const int stride = gridDim.x * blockDim.x;
    for (int i = blockIdx.x * blockDim.x + threadIdx.x; i < limit; i += stride) {
        const float4 fv = f[base + i];
        float4 p;
        if (pbuf) {
            p = pbuf[base + i];
        } else {
            const float4 gv = g[base + i];
            p.x = fv.x * gv.x; p.y = fv.y * gv.y; p.z = fv.z * gv.z; p.w = fv.w * gv.w;
        }
        float4 o;
        o.x = (p.x > thr) ? 0.0f : fv.x;
        o.y = (p.y > thr) ? 0.0f : fv.y;
        o.z = (p.z > thr) ? 0.0f : fv.z;
        o.w = (p.w > thr) ? 0.0f : fv.w;
        out[base + i] = o;
    }
}

// Covers the last tailCut float4 of the last sample, where small scratch arrays lived
// (only used in the no-workspace fallback). Single block: read thr, sync, then overwrite.
__global__ void apply_tail_kernel(const float4* __restrict__ f, const float4* __restrict__ g,
                                  const float* __restrict__ thrF,
                                  float4* __restrict__ out, int tailCut) {
    const float thr = thrF[NS - 1];
    asm volatile("" :: "v"(thr));   // force load to complete before the barrier
    __syncthreads();
    const int t = threadIdx.x;
    const size_t base = (size_t)NS * NPSV - tailCut;
    if (t < tailCut) {
        const float4 fv = f[base + t];
        const float4 gv = g[base + t];
        float4 p;
        p.x = fv.x * gv.x; p.y = fv.y * gv.y; p.z = fv.z * gv.z; p.w = fv.w * gv.w;
        float4 o;
        o.x = (p.x > thr) ? 0.0f : fv.x;
        o.y = (p.y > thr) ? 0.0f : fv.y;
        o.z = (p.z > thr) ? 0.0f : fv.z;
        o.w = (p.w > thr) ? 0.0f : fv.w;
        out[base + t] = o;
    }
}

extern "C" void kernel_launch(void* const* d_in, const int* in_sizes, int n_in,
                              void* d_out, int out_size, void* d_ws, size_t ws_size,
                              hipStream_t stream) {
    const float* f = (const float*)d_in[0];   // features
    const float* g = (const float*)d_in[1];   // grad
    float* out = (float*)d_out;

    const size_t histBytes  = (size_t)NS * HB * sizeof(unsigned);  // 16 MB each
    const size_t smallBytes = 3 * NS * sizeof(unsigned);           // 768 B

    unsigned *hist1, *hist2, *candBin, *kRemA;
    float* thrF;
    float4* pbuf = nullptr;
    int tailCut = 0;

    if (ws_size >= 2 * histBytes + smallBytes) {
        // Plan A: histograms+smalls in ws, product stashed in d_out (reused as scratch)
        char* w = (char*)d_ws;
        hist1   = (unsigned*)w;
        hist2   = (unsigned*)(w + histBytes);
        candBin = (unsigned*)(w + 2 * histBytes);
        kRemA   = candBin + NS;
        thrF    = (float*)(kRemA + NS);
        pbuf    = (float4*)out;
    } else if (ws_size >= smallBytes) {
        // Plan B: histograms in d_out (overwritten by apply), smalls in ws, recompute p
        hist1   = (unsigned*)out;
        hist2   = hist1 + (size_t)NS * HB;
        candBin = (unsigned*)d_ws;
        kRemA   = candBin + NS;
        thrF    = (float*)(kRemA + NS);
    } else {
        // Plan C: everything in d_out; smalls at the very end, fixed up by tail kernel
        hist1   = (unsigned*)out;
        hist2   = hist1 + (size_t)NS * HB;
        unsigned* smalls = (unsigned*)out + ((size_t)NS * NPS - 192);
        candBin = smalls;
        kRemA   = smalls + NS;
        thrF    = (float*)(smalls + 2 * NS);
        tailCut = 48;  // 192 floats = 48 float4
    }

    // zero both histograms (contiguous in every plan)
    zero4_kernel<<<2048, 256, 0, stream>>>((uint4*)hist1, (int)(2 * histBytes / 16));

    dim3 gh(GX, NS);
    hist_hi_kernel<<<gh, 256, 0, stream>>>((const float4*)f, (const float4*)g, pbuf, hist1);
    scan_hi_kernel<<<NS, 256, 0, stream>>>(hist1, candBin, kRemA);
    hist_lo_kernel<<<gh, 256, 0, stream>>>((const float4*)f, (const float4*)g, pbuf, candBin, hist2);
    scan_lo_kernel<<<NS, 256, 0, stream>>>(hist2, candBin, kRemA, thrF);
    apply_kernel<<<gh, 256, 0, stream>>>((const float4*)f, (const float4*)g, pbuf, thrF,
                                         (float4*)out, tailCut);
    if (tailCut > 0) {
        apply_tail_kernel<<<1, 256, 0, stream>>>((const float4*)f, (const float4*)g, thrF,
                                                 (float4*)out, tailCut);
    }
}

// Round 2
// 350.623 us; speedup vs baseline: 4.4786x; 4.4786x over previous
//
#include <hip/hip_runtime.h>
#include <hip/hip_bf16.h>

namespace {
constexpr int NS   = 64;           // batch
constexpr int NPS  = 802816;       // elements per sample (256*56*56)
constexpr int NPSV = NPS / 4;      // float4 per sample
constexpr unsigned KSEL = 80281u;  // int(0.1 * 802816)
constexpr unsigned SENTINEL = 0xFFFFFFFFu;
constexpr int GX  = 24;            // blocks per sample, histogram passes
constexpr int GXA = 64;            // blocks per sample, apply pass
constexpr int NB1 = 4096;          // level 1: bits 19..30 (exp + 4 mantissa)
constexpr int NB2 = 8192;          // level 2: bits 6..18
constexpr int NB3 = 64;            // level 3: bits 0..5
}

// ---------------- level-1 histogram: p = f*g, stash p, LDS hist of u>>19 ----------
__global__ __launch_bounds__(256) void hist1_kernel(const float4* __restrict__ f,
                                                    const float4* __restrict__ g,
                                                    float4* __restrict__ pout,
                                                    unsigned short* __restrict__ bh) {
    __shared__ unsigned h[NB1];
    const int t = threadIdx.x;
    for (int k = t; k < NB1; k += 256) h[k] = 0u;
    __syncthreads();
    const int b = blockIdx.y;
    const size_t base = (size_t)b * NPSV;
    const int stride = gridDim.x * blockDim.x;
    const bool store = (pout != nullptr);
    for (int i = blockIdx.x * 256 + t; i < NPSV; i += stride) {
        const float4 fv = f[base + i];
        const float4 gv = g[base + i];
        float4 p;
        p.x = fv.x * gv.x; p.y = fv.y * gv.y; p.z = fv.z * gv.z; p.w = fv.w * gv.w;
        if (store) pout[base + i] = p;
        if (p.x > 0.0f) atomicAdd(&h[__float_as_uint(p.x) >> 19], 1u);
        if (p.y > 0.0f) atomicAdd(&h[__float_as_uint(p.y) >> 19], 1u);
        if (p.z > 0.0f) atomicAdd(&h[__float_as_uint(p.z) >> 19], 1u);
        if (p.w > 0.0f) atomicAdd(&h[__float_as_uint(p.w) >> 19], 1u);
    }
    __syncthreads();
    unsigned short* o = bh + (size_t)(b * GX + blockIdx.x) * NB1;
    for (int k = t; k < NB1; k += 256) o[k] = (unsigned short)h[k];  // count <= 50176, fits
}

// ---------------- level-2 histogram: filter u>>19 == c1, hist (u>>6)&8191 ---------
__global__ __launch_bounds__(256) void hist2_kernel(const float4* __restrict__ f,
                                                    const float4* __restrict__ g,
                                                    const float4* __restrict__ pbuf,
                                                    const unsigned* __restrict__ c1,
                                                    unsigned short* __restrict__ bh) {
    __shared__ unsigned h[NB2];
    const int t = threadIdx.x;
    for (int k = t; k < NB2; k += 256) h[k] = 0u;
    __syncthreads();
    const int b = blockIdx.y;
    const unsigned cb = c1[b];
    const size_t base = (size_t)b * NPSV;
    const int stride = gridDim.x * blockDim.x;
    for (int i = blockIdx.x * 256 + t; i < NPSV; i += stride) {
        float4 p;
        if (pbuf) {
            p = pbuf[base + i];
        } else {
            const float4 fv = f[base + i];
            const float4 gv = g[base + i];
            p.x = fv.x * gv.x; p.y = fv.y * gv.y; p.z = fv.z * gv.z; p.w = fv.w * gv.w;
        }
#define H2(c) { if ((c) > 0.0f) { unsigned u = __float_as_uint(c); \
                if ((u >> 19) == cb) atomicAdd(&h[(u >> 6) & (NB2 - 1)], 1u); } }
        H2(p.x) H2(p.y) H2(p.z) H2(p.w)
#undef H2
    }
    __syncthreads();
    unsigned short* o = bh + (size_t)(b * GX + blockIdx.x) * NB2;
    for (int k = t; k < NB2; k += 256) o[k] = (unsigned short)h[k];
}

// ---------------- level-3 histogram: filter u>>6 == c2, hist u&63 -----------------
__global__ __launch_bounds__(256) void hist3_kernel(const float4* __restrict__ f,
                                                    const float4* __restrict__ g,
                                                    const float4* __restrict__ pbuf,
                                                    const unsigned* __restrict__ c2,
                                                    unsigned short* __restrict__ bh) {
    __shared__ unsigned h[NB3];
    const int t = threadIdx.x;
    if (t < NB3) h[t] = 0u;
    __syncthreads();
    const int b = blockIdx.y;
    const unsigned cb = c2[b];
    const size_t base = (size_t)b * NPSV;
    const int stride = gridDim.x * blockDim.x;
    for (int i = blockIdx.x * 256 + t; i < NPSV; i += stride) {
        float4 p;
        if (pbuf) {
            p = pbuf[base + i];
        } else {
            const float4 fv = f[base + i];
            const float4 gv = g[base + i];
            p.x = fv.x * gv.x; p.y = fv.y * gv.y; p.z = fv.z * gv.z; p.w = fv.w * gv.w;
        }
#define H3(c) { if ((c) > 0.0f) { unsigned u = __float_as_uint(c); \
                if ((u >> 6) == cb) atomicAdd(&h[u & 63u], 1u); } }
        H3(p.x) H3(p.y) H3(p.z) H3(p.w)
#undef H3
    }
    __syncthreads();
    unsigned short* o = bh + (size_t)(b * GX + blockIdx.x) * NB3;
    if (t < NB3) o[t] = (unsigned short)h[t];
}

// ---------------- selection within an LDS histogram -------------------------------
// Find bin B with suffix(B) < K <= suffix(B)+h[B], suffix = count strictly above B.
template <int NB>
__device__ void select_in_lds(const unsigned* __restrict__ h, unsigned K,
                              unsigned* bin, unsigned* rem) {
    constexpr int BPT = NB / 256;
    __shared__ unsigned cs[256];
    __shared__ unsigned fB, fR;
    const int t = threadIdx.x;
    if (t == 0) { fB = SENTINEL; fR = 0u; }
    unsigned s = 0;
    for (int j = 0; j < BPT; ++j) s += h[t * BPT + j];
    cs[t] = s;
    __syncthreads();
    unsigned suf = 0;
    for (int j = t + 1; j < 256; ++j) suf += cs[j];
    if (suf < K && suf + s >= K) {   // exactly one chunk crosses
        unsigned cur = suf;
        for (int j = BPT - 1; j >= 0; --j) {
            const unsigned c = h[t * BPT + j];
            if (cur < K && cur + c >= K) { fB = (unsigned)(t * BPT + j); fR = K - cur; break; }
            cur += c;
        }
    }
    __syncthreads();
    *bin = fB; *rem = fR;
}

__global__ __launch_bounds__(256) void scan1_kernel(const unsigned short* __restrict__ bh,
                                                    unsigned* __restrict__ c1,
                                                    unsigned* __restrict__ r1) {
    __shared__ unsigned h[NB1];
    const int b = blockIdx.x, t = threadIdx.x;
    for (int k = t; k < NB1; k += 256) {
        unsigned s = 0;
        const unsigned short* p = bh + (size_t)b * GX * NB1 + k;
        for (int j = 0; j < GX; ++j) s += p[(size_t)j * NB1];
        h[k] = s;
    }
    __syncthreads();
    unsigned bin, rem;
    select_in_lds<NB1>(h, KSEL, &bin, &rem);
    if (t == 0) { c1[b] = bin; r1[b] = rem; }
}

__global__ __launch_bounds__(256) void scan2_kernel(const unsigned short* __restrict__ bh,
                                                    const unsigned* __restrict__ c1,
                                                    const unsigned* __restrict__ r1,
                                                    unsigned* __restrict__ c2,
                                                    unsigned* __restrict__ r2) {
    const int b = blockIdx.x, t = threadIdx.x;
    if (c1[b] == SENTINEL) {           // fewer than K positives -> threshold is 0
        if (t == 0) { c2[b] = SENTINEL; r2[b] = 0u; }
        return;
    }
    __shared__ unsigned h[NB2];
    for (int k = t; k < NB2; k += 256) {
        unsigned s = 0;
        const unsigned short* p = bh + (size_t)b * GX * NB2 + k;
        for (int j = 0; j < GX; ++j) s += p[(size_t)j * NB2];
        h[k] = s;
    }
    __syncthreads();
    unsigned bin, rem;
    select_in_lds<NB2>(h, r1[b], &bin, &rem);
    if (t == 0) { c2[b] = (c1[b] << 13) | bin; r2[b] = rem; }
}

__global__ __launch_bounds__(256) void scan3_kernel(const unsigned short* __restrict__ bh,
                                                    const unsigned* __restrict__ c2,
                                                    const unsigned* __restrict__ r2,
                                                    float* __restrict__ thrF) {
    const int b = blockIdx.x, t = threadIdx.x;
    if (c2[b] == SENTINEL) {
        if (t == 0) thrF[b] = 0.0f;
        return;
    }
    __shared__ unsigned h[NB3];
    if (t < NB3) {
        unsigned s = 0;
        const unsigned short* p = bh + (size_t)b * GX * NB3 + t;
        for (int j = 0; j < GX; ++j) s += p[j * NB3];
        h[t] = s;
    }
    __syncthreads();
    if (t == 0) {
        const unsigned K = r2[b];
        unsigned cur = 0, bin = 0;
        for (int j = NB3 - 1; j >= 0; --j) {
            const unsigned c = h[j];
            if (cur < K && cur + c >= K) { bin = (unsigned)j; break; }
            cur += c;
        }
        thrF[b] = __uint_as_float((c2[b] << 6) | bin);
    }
}

// ---------------- apply: out = (p > thr) ? 0 : f ----------------------------------
__global__ __launch_bounds__(256) void apply_kernel(const float4* __restrict__ f,
                                                    const float4* __restrict__ g,
                                                    const float4* __restrict__ pbuf,
                                                    const float* __restrict__ thrF,
                                                    float4* __restrict__ out, int tailCut) {
    const int b = blockIdx.y;
    const float thr = thrF[b];
    const size_t base = (size_t)b * NPSV;
    const int limit = NPSV - ((b == NS - 1) ? tailCut : 0);
    const int stride = gridDim.x * blockDim.x;
    for (int i = blockIdx.x * 256 + threadIdx.x; i < limit; i += stride) {
        const float4 fv = f[base + i];
        float4 p;
        if (pbuf) {
            p = pbuf[base + i];
        } else {
            const float4 gv = g[base + i];
            p.x = fv.x * gv.x; p.y = fv.y * gv.y; p.z = fv.z * gv.z; p.w = fv.w * gv.w;
        }
        float4 o;
        o.x = (p.x > thr) ? 0.0f : fv.x;
        o.y = (p.y > thr) ? 0.0f : fv.y;
        o.z = (p.z > thr) ? 0.0f : fv.z;
        o.w = (p.w > thr) ? 0.0f : fv.w;
        out[base + i] = o;
    }
}

// Plan-C fixup: last tailCut float4 of the last sample (where smalls lived)
__global__ void apply_tail_kernel(const float4* __restrict__ f, const float4* __restrict__ g,
                                  const float* __restrict__ thrF,
                                  float4* __restrict__ out, int tailCut) {
    const float thr = thrF[NS - 1];
    asm volatile("" :: "v"(thr));
    __syncthreads();
    const int t = threadIdx.x;
    const size_t base = (size_t)NS * NPSV - tailCut;
    if (t < tailCut) {
        const float4 fv = f[base + t];
        const float4 gv = g[base + t];
        float4 p;
        p.x = fv.x * gv.x; p.y = fv.y * gv.y; p.z = fv.z * gv.z; p.w = fv.w * gv.w;
        float4 o;
        o.x = (p.x > thr) ? 0.0f : fv.x;
        o.y = (p.y > thr) ? 0.0f : fv.y;
        o.z = (p.z > thr) ? 0.0f : fv.z;
        o.w = (p.w > thr) ? 0.0f : fv.w;
        out[base + t] = o;
    }
}

extern "C" void kernel_launch(void* const* d_in, const int* in_sizes, int n_in,
                              void* d_out, int out_size, void* d_ws, size_t ws_size,
                              hipStream_t stream) {
    const float* f = (const float*)d_in[0];
    const float* g = (const float*)d_in[1];
    float* out = (float*)d_out;

    // block-histogram scratch: sized for the largest level (NB2), reused by all levels
    const size_t bhBytes    = (size_t)NS * GX * NB2 * sizeof(unsigned short);  // 24 MB
    const size_t smallBytes = 5 * NS * sizeof(unsigned);                        // 1280 B

    unsigned short* bh;
    unsigned *c1, *r1, *c2, *r2;
    float* thrF;
    float4* pbuf = nullptr;
    int tailCut = 0;

    if (ws_size >= bhBytes + smallBytes) {
        // Plan A: hists + smalls in ws; product stashed in d_out (overwritten by apply)
        char* w = (char*)d_ws;
        bh   = (unsigned short*)w;
        c1   = (unsigned*)(w + bhBytes);
        r1   = c1 + NS; c2 = r1 + NS; r2 = c2 + NS;
        thrF = (float*)(r2 + NS);
        pbuf = (float4*)out;
    } else if (ws_size >= smallBytes) {
        // Plan B: hists in d_out head, smalls in ws, recompute p each pass
        bh   = (unsigned short*)out;
        c1   = (unsigned*)d_ws;
        r1   = c1 + NS; c2 = r1 + NS; r2 = c2 + NS;
        thrF = (float*)(r2 + NS);
    } else {
        // Plan C: hists in d_out head, smalls at d_out tail (fixed up afterwards)
        bh   = (unsigned short*)out;
        unsigned* smalls = (unsigned*)out + ((size_t)NS * NPS - 320);
        c1   = smalls; r1 = c1 + NS; c2 = r1 + NS; r2 = c2 + NS;
        thrF = (float*)(r2 + NS);
        tailCut = 80;  // 320 floats = 80 float4
    }

    const dim3 gh(GX, NS);
    hist1_kernel<<<gh, 256, 0, stream>>>((const float4*)f, (const float4*)g, pbuf, bh);
    scan1_kernel<<<NS, 256, 0, stream>>>(bh, c1, r1);
    hist2_kernel<<<gh, 256, 0, stream>>>((const float4*)f, (const float4*)g, pbuf, c1, bh);
    scan2_kernel<<<NS, 256, 0, stream>>>(bh, c1, r1, c2, r2);
    hist3_kernel<<<gh, 256, 0, stream>>>((const float4*)f, (const float4*)g, pbuf, c2, bh);
    scan3_kernel<<<NS, 256, 0, stream>>>(bh, c2, r2, thrF);
    apply_kernel<<<dim3(GXA, NS), 256, 0, stream>>>((const float4*)f, (const float4*)g, pbuf,
                                                    thrF, (float4*)out, tailCut);
    if (tailCut > 0) {
        apply_tail_kernel<<<1, 256, 0, stream>>>((const float4*)f, (const float4*)g, thrF,
                                                 (float4*)out, tailCut);
    }
}